// Round 2
// baseline (149.043 us; speedup 1.0000x reference)
//
#include <hip/hip_runtime.h>
#include <hip/hip_bf16.h>

#define B_   32
#define C_   16
#define H_   256
#define W_   256
#define HW_  65536      // H_*W_
#define HID_ 128
#define NSTRIP_ (B_*HW_/64)   // 32768 strips of 64 pixels

typedef __attribute__((ext_vector_type(8))) short bf16x8;
typedef __attribute__((ext_vector_type(4))) float f32x4;

__device__ __forceinline__ short f2bf(float f) {
    __hip_bfloat16 h = __float2bfloat16(f);
    return __builtin_bit_cast(short, h);
}

// ---------------- prep: fold w1 into per-o {A,B,C,b1} ------------------------
__global__ __launch_bounds__(128) void nca_prep(
    const float* __restrict__ w1, const float* __restrict__ b1,
    float4* __restrict__ coef4)
{
    int o = threadIdx.x;   // 0..127
    float A = 0.f, Bc = 0.f, Cc = 0.f;
    #pragma unroll
    for (int k = 0;  k < 16; ++k) A  += w1[o*48 + k];
    #pragma unroll
    for (int k = 16; k < 32; ++k) Bc += w1[o*48 + k];
    #pragma unroll
    for (int k = 32; k < 48; ++k) Cc += w1[o*48 + k];
    coef4[o] = make_float4(A, Bc, Cc, b1[o]);
}

// ---------------- k1: xs[b,p] = sum over 16 channels, float4 vectorized ------
__global__ __launch_bounds__(256) void nca_sum(
    const float* __restrict__ x, float* __restrict__ xs)
{
    int t = blockIdx.x * blockDim.x + threadIdx.x;   // float4 index
    if (t >= B_*HW_/4) return;
    int b  = t >> 14;
    int p4 = (t << 2) & (HW_-1);
    const float* xp = x + (size_t)b * C_ * HW_ + p4;
    float4 s = make_float4(0.f, 0.f, 0.f, 0.f);
    #pragma unroll
    for (int c = 0; c < C_; ++c) {
        float4 v = *(const float4*)(xp + (size_t)c * HW_);
        s.x += v.x; s.y += v.y; s.z += v.z; s.w += v.w;
    }
    ((float4*)xs)[t] = s;
}

// ---------------- k2: sobel + MLP (layer2 = MFMA) + update + alpha flag ------
// One wave handles a strip of 64 consecutive pixels in one image row.
// Phase 1 (per lane = per pixel): sobel + layer-1 h (scalar coefs via s_load).
// h -> bf16 -> per-wave LDS tile -> MFMA B-frags; A = w2 (bf16, in regs).
__global__ __launch_bounds__(256) void nca_mlp(
    const float* __restrict__ x, const int* __restrict__ mask,
    const float* __restrict__ xs, const float4* __restrict__ coef4,
    const float* __restrict__ w2, const float* __restrict__ b2,
    float* __restrict__ out, unsigned char* __restrict__ alpha)
{
    // per-wave: 2 ping-pong regions of [64 px][32 h] bf16 = 2*4KB; 4 waves = 32KB
    __shared__ short hlds[4*2*2048];

    const int tid  = threadIdx.x;
    const int lane = tid & 63;
    const int widx = tid >> 6;
    const int q = lane & 15;       // MFMA col lane (pixel-within-group / A-row ch)
    const int g = lane >> 4;       // MFMA k-group

    // A-fragments: w2[ch=q][k = kb*32 + g*8 + j] -> bf16
    bf16x8 afrag[4];
    #pragma unroll
    for (int kb = 0; kb < 4; ++kb) {
        const float* wp = w2 + q*HID_ + kb*32 + g*8;
        bf16x8 a;
        #pragma unroll
        for (int j = 0; j < 8; ++j) a[j] = f2bf(wp[j]);
        afrag[kb] = a;
    }
    float b2v[4];
    #pragma unroll
    for (int r = 0; r < 4; ++r) b2v[r] = b2[g*4 + r];

    const int wswz = (lane ^ (lane >> 2)) & 3;     // write-side chunk swizzle
    const int rsw  = (q ^ (q >> 2)) & 3;           // read-side swizzle component
    short* hbase = hlds + widx*4096;

    const int wgid = (blockIdx.x*256 + tid) >> 6;
    const int nw   = (gridDim.x*256) >> 6;

    for (int s = wgid; s < NSTRIP_; s += nw) {
        const int b = s >> 10;                     // 1024 strips per image
        const int pixbase = (s & 1023) << 6;
        const int i  = pixbase >> 8;               // row
        const int jj = (pixbase & (W_-1)) + lane;  // column of this lane's pixel
        const int p  = i*W_ + jj;
        const float* xsb = xs + (size_t)b * HW_;

        const bool im = i > 0, ip = i < H_-1, jm = jj > 0, jp = jj < W_-1;
        float n11 = xsb[p];
        float n10 = jm ? xsb[p-1]  : 0.f;
        float n12 = jp ? xsb[p+1]  : 0.f;
        float n01 = im ? xsb[p-W_] : 0.f;
        float n00 = (im && jm) ? xsb[p-W_-1] : 0.f;
        float n02 = (im && jp) ? xsb[p-W_+1] : 0.f;
        float n21 = ip ? xsb[p+W_] : 0.f;
        float n20 = (ip && jm) ? xsb[p+W_-1] : 0.f;
        float n22 = (ip && jp) ? xsb[p+W_+1] : 0.f;
        float px = (n02 - n00) + 2.f*(n12 - n10) + (n22 - n20);
        float py = (n20 - n00) + 2.f*(n21 - n01) + (n22 - n02);
        float sc = n11;

        f32x4 acc[4];
        #pragma unroll
        for (int t = 0; t < 4; ++t) acc[t] = (f32x4){0.f, 0.f, 0.f, 0.f};

        #pragma unroll
        for (int kb = 0; kb < 4; ++kb) {
            short* hw = hbase + (kb & 1)*2048;
            // layer 1: 32 hidden values for this lane's pixel; coef4[o] is
            // wave-uniform (compile-time o) -> scalar loads
            #pragma unroll
            for (int c = 0; c < 4; ++c) {
                bf16x8 hv;
                #pragma unroll
                for (int u = 0; u < 8; ++u) {
                    const float4 cf = coef4[kb*32 + c*8 + u];
                    float h = fmaf(cf.x, px, fmaf(cf.y, py, fmaf(cf.z, sc, cf.w)));
                    hv[u] = f2bf(fmaxf(h, 0.f));
                }
                *(bf16x8*)(hw + lane*32 + ((c ^ wswz) << 3)) = hv;
            }
            // MFMA: 4 groups of 16 pixels, B-frag = h[kb*32+g*8+j][t*16+q]
            #pragma unroll
            for (int t = 0; t < 4; ++t) {
                const int pp = t*16 + q;
                bf16x8 bfrag = *(const bf16x8*)(hw + pp*32 + (((g ^ rsw) & 3) << 3));
                acc[t] = __builtin_amdgcn_mfma_f32_16x16x32_bf16(
                             afrag[kb], bfrag, acc[t], 0, 0, 0);
            }
        }

        // epilogue: lane holds dx[ch=g*4+r][pixel=t*16+q]
        #pragma unroll
        for (int t = 0; t < 4; ++t) {
            const int pp = pixbase + t*16 + q;
            const float m = (float)mask[b*HW_ + pp];
            const size_t xb = (size_t)b * C_ * HW_ + pp;
            float xn3 = 0.f;
            #pragma unroll
            for (int r = 0; r < 4; ++r) {
                const int ch = g*4 + r;
                float xn = fmaf(acc[t][r] + b2v[r], m, x[xb + (size_t)ch * HW_]);
                out[xb + (size_t)ch * HW_] = xn;
                if (ch == 3) xn3 = xn;
            }
            if (g == 0) alpha[b*HW_ + pp] = (xn3 > 0.1f) ? (unsigned char)1
                                                         : (unsigned char)0;
        }
    }
}

// ---------------- k3: kill pixels with no alive neighbor ---------------------
__global__ __launch_bounds__(256) void nca_alive(
    const unsigned char* __restrict__ alpha, float* __restrict__ out)
{
    int t = blockIdx.x * blockDim.x + threadIdx.x;
    if (t >= B_*HW_) return;
    int b = t >> 16;
    int p = t & (HW_-1);
    int i = p >> 8;
    int j = p & (W_-1);
    const unsigned char* ab = alpha + (size_t)b * HW_;

    bool im = i > 0, ip = i < H_-1, jm = j > 0, jp = j < W_-1;
    int acc = ab[p];
    acc += jm ? ab[p-1] : 0;
    acc += jp ? ab[p+1] : 0;
    if (im) {
        acc += ab[p-W_];
        acc += jm ? ab[p-W_-1] : 0;
        acc += jp ? ab[p-W_+1] : 0;
    }
    if (ip) {
        acc += ab[p+W_];
        acc += jm ? ab[p+W_-1] : 0;
        acc += jp ? ab[p+W_+1] : 0;
    }
    if (acc == 0) {
        size_t base = (size_t)b * C_ * HW_ + p;
        #pragma unroll
        for (int c = 0; c < C_; ++c) out[base + (size_t)c * HW_] = 0.f;
    }
}

extern "C" void kernel_launch(void* const* d_in, const int* in_sizes, int n_in,
                              void* d_out, int out_size, void* d_ws, size_t ws_size,
                              hipStream_t stream)
{
    const float* x    = (const float*)d_in[0];
    const int*   mask = (const int*)d_in[1];
    const float* w1   = (const float*)d_in[2];
    const float* b1   = (const float*)d_in[3];
    const float* w2   = (const float*)d_in[4];
    const float* b2   = (const float*)d_in[5];
    float* out = (float*)d_out;

    // ws layout: xs (B*HW floats) | alpha (B*HW bytes) | coef4 (128 float4)
    char* ws = (char*)d_ws;
    float*         xsbuf = (float*)ws;
    unsigned char* alpha = (unsigned char*)(ws + (size_t)B_*HW_*4);
    float4*        coef4 = (float4*)(ws + (size_t)B_*HW_*5);

    nca_prep<<<1, 128, 0, stream>>>(w1, b1, coef4);

    int n4 = B_*HW_/4;
    nca_sum<<<(n4 + 255)/256, 256, 0, stream>>>(x, xsbuf);

    nca_mlp<<<2048, 256, 0, stream>>>(x, mask, xsbuf, coef4, w2, b2, out, alpha);

    int n = B_*HW_;
    nca_alive<<<(n + 255)/256, 256, 0, stream>>>(alpha, out);
}

// Round 3
// 106.088 us; speedup vs baseline: 1.4049x; 1.4049x over previous
//
#include <hip/hip_runtime.h>
#include <hip/hip_bf16.h>

#define B_   32
#define C_   16
#define H_   256
#define W_   256
#define HW_  65536      // H_*W_
#define HID_ 128
#define NSTRIP_ (B_*HW_/64)   // 32768 strips of 64 pixels

typedef __attribute__((ext_vector_type(8))) short bf16x8;
typedef __attribute__((ext_vector_type(4))) float f32x4;

__device__ __forceinline__ short f2bf(float f) {
    __hip_bfloat16 h = __float2bfloat16(f);
    return __builtin_bit_cast(short, h);
}

// hardware packed f32->bf16 RNE (no builtin on gfx950; guide §T12)
__device__ __forceinline__ int cvt_pk_bf16(float lo, float hi) {
    int r;
    asm("v_cvt_pk_bf16_f32 %0, %1, %2" : "=v"(r) : "v"(lo), "v"(hi));
    return r;
}

// ---------------- prep: fold w1 into per-o {A,B,C,b1} ------------------------
__global__ __launch_bounds__(128) void nca_prep(
    const float* __restrict__ w1, const float* __restrict__ b1,
    float4* __restrict__ coef4)
{
    int o = threadIdx.x;   // 0..127
    float A = 0.f, Bc = 0.f, Cc = 0.f;
    #pragma unroll
    for (int k = 0;  k < 16; ++k) A  += w1[o*48 + k];
    #pragma unroll
    for (int k = 16; k < 32; ++k) Bc += w1[o*48 + k];
    #pragma unroll
    for (int k = 32; k < 48; ++k) Cc += w1[o*48 + k];
    coef4[o] = make_float4(A, Bc, Cc, b1[o]);
}

// ---------------- k1: xs[b,p] = sum over 16 channels, float4 vectorized ------
__global__ __launch_bounds__(256) void nca_sum(
    const float* __restrict__ x, float* __restrict__ xs)
{
    int t = blockIdx.x * blockDim.x + threadIdx.x;   // float4 index
    if (t >= B_*HW_/4) return;
    int b  = t >> 14;
    int p4 = (t << 2) & (HW_-1);
    const float* xp = x + (size_t)b * C_ * HW_ + p4;
    float4 s = make_float4(0.f, 0.f, 0.f, 0.f);
    #pragma unroll
    for (int c = 0; c < C_; ++c) {
        float4 v = *(const float4*)(xp + (size_t)c * HW_);
        s.x += v.x; s.y += v.y; s.z += v.z; s.w += v.w;
    }
    ((float4*)xs)[t] = s;
}

// ---------------- k2: sobel + MLP (layer2 = MFMA) + update + alpha flag ------
// One wave = one 64-pixel strip of a row. Per lane: sobel + 128 hidden units
// (wave-uniform coefs -> s_load). h -> bf16 via v_cvt_pk -> 4KB wave-private
// LDS tile -> MFMA B-frags. A-frags = w2 rows (bf16, hoisted).
// x/mask prefetched at loop top so HBM latency hides under layer-1 VALU.
__global__ __launch_bounds__(256, 5) void nca_mlp(
    const float* __restrict__ x, const int* __restrict__ mask,
    const float* __restrict__ xs, const float4* __restrict__ coef4,
    const float* __restrict__ w2, const float* __restrict__ b2,
    float* __restrict__ out, unsigned char* __restrict__ alpha)
{
    // per-wave single region [64 px][32 h] bf16 = 4KB; 4 waves = 16KB/block
    __shared__ short hlds[4*2048];

    const int tid  = threadIdx.x;
    const int lane = tid & 63;
    const int widx = tid >> 6;
    const int q = lane & 15;       // MFMA col lane (pixel-within-group / A-row ch)
    const int g = lane >> 4;       // MFMA k-group

    // A-fragments: w2[ch=q][k = kb*32 + g*8 + j] -> bf16 (setup, once)
    bf16x8 afrag[4];
    #pragma unroll
    for (int kb = 0; kb < 4; ++kb) {
        const float* wp = w2 + q*HID_ + kb*32 + g*8;
        bf16x8 a;
        #pragma unroll
        for (int j = 0; j < 8; ++j) a[j] = f2bf(wp[j]);
        afrag[kb] = a;
    }
    float b2v[4];
    #pragma unroll
    for (int r = 0; r < 4; ++r) b2v[r] = b2[g*4 + r];

    const int wswz = (lane ^ (lane >> 2)) & 3;     // write-side chunk swizzle
    const int rsw  = (q ^ (q >> 2)) & 3;           // read-side swizzle component
    short* hw = hlds + widx*2048;

    const int wgid = (blockIdx.x*256 + tid) >> 6;
    const int nw   = (gridDim.x*256) >> 6;

    for (int s = wgid; s < NSTRIP_; s += nw) {
        const int b = s >> 10;                     // 1024 strips per image
        const int pixbase = (s & 1023) << 6;
        const int i  = pixbase >> 8;               // row
        const int jj = (pixbase & (W_-1)) + lane;  // column of this lane's pixel
        const int p  = i*W_ + jj;

        // ---- prefetch epilogue inputs (independent -> issue before compute) --
        const size_t xb0 = (size_t)b * C_ * HW_ + pixbase;
        float xv[4][4];
        float mv[4];
        #pragma unroll
        for (int t = 0; t < 4; ++t) {
            const int pp = t*16 + q;
            mv[t] = (float)mask[b*HW_ + pixbase + pp];
            #pragma unroll
            for (int r = 0; r < 4; ++r)
                xv[t][r] = x[xb0 + (size_t)(g*4 + r) * HW_ + pp];
        }

        // ---- sobel on channel-sum ----
        const float* xsb = xs + (size_t)b * HW_;
        const bool im = i > 0, ip = i < H_-1, jm = jj > 0, jp = jj < W_-1;
        float n11 = xsb[p];
        float n10 = jm ? xsb[p-1]  : 0.f;
        float n12 = jp ? xsb[p+1]  : 0.f;
        float n01 = im ? xsb[p-W_] : 0.f;
        float n00 = (im && jm) ? xsb[p-W_-1] : 0.f;
        float n02 = (im && jp) ? xsb[p-W_+1] : 0.f;
        float n21 = ip ? xsb[p+W_] : 0.f;
        float n20 = (ip && jm) ? xsb[p+W_-1] : 0.f;
        float n22 = (ip && jp) ? xsb[p+W_+1] : 0.f;
        float px = (n02 - n00) + 2.f*(n12 - n10) + (n22 - n20);
        float py = (n20 - n00) + 2.f*(n21 - n01) + (n22 - n02);
        float sc = n11;

        f32x4 acc[4];
        #pragma unroll
        for (int t = 0; t < 4; ++t) acc[t] = (f32x4){0.f, 0.f, 0.f, 0.f};

        #pragma unroll
        for (int kb = 0; kb < 4; ++kb) {
            // layer 1: 32 hidden values for this lane's pixel; coef4[o] has a
            // compile-time uniform index -> scalar loads
            #pragma unroll
            for (int c = 0; c < 4; ++c) {
                float h[8];
                #pragma unroll
                for (int u = 0; u < 8; ++u) {
                    const float4 cf = coef4[kb*32 + c*8 + u];
                    h[u] = fmaxf(fmaf(cf.x, px, fmaf(cf.y, py, fmaf(cf.z, sc, cf.w))), 0.f);
                }
                int4 hd = make_int4(cvt_pk_bf16(h[0], h[1]), cvt_pk_bf16(h[2], h[3]),
                                    cvt_pk_bf16(h[4], h[5]), cvt_pk_bf16(h[6], h[7]));
                *(int4*)(hw + lane*32 + ((c ^ wswz) << 3)) = hd;
            }
            __builtin_amdgcn_wave_barrier();   // order cross-lane LDS w->r (free)
            // MFMA: 4 groups of 16 pixels, B-frag = h[kb*32+g*8+j][t*16+q]
            #pragma unroll
            for (int t = 0; t < 4; ++t) {
                const int pp = t*16 + q;
                bf16x8 bfrag = *(const bf16x8*)(hw + pp*32 + (((g ^ rsw) & 3) << 3));
                acc[t] = __builtin_amdgcn_mfma_f32_16x16x32_bf16(
                             afrag[kb], bfrag, acc[t], 0, 0, 0);
            }
            __builtin_amdgcn_wave_barrier();   // keep next kb's writes after reads
        }

        // epilogue: lane holds dx[ch=g*4+r][pixel=t*16+q]
        #pragma unroll
        for (int t = 0; t < 4; ++t) {
            const int pp = pixbase + t*16 + q;
            const size_t xb = (size_t)b * C_ * HW_ + pp;
            float xn3 = 0.f;
            #pragma unroll
            for (int r = 0; r < 4; ++r) {
                const int ch = g*4 + r;
                float xn = fmaf(acc[t][r] + b2v[r], mv[t], xv[t][r]);
                out[xb + (size_t)ch * HW_] = xn;
                if (ch == 3) xn3 = xn;
            }
            if (g == 0) alpha[b*HW_ + pp] = (xn3 > 0.1f) ? (unsigned char)1
                                                         : (unsigned char)0;
        }
    }
}

// ---------------- k3: kill pixels with no alive neighbor ---------------------
__global__ __launch_bounds__(256) void nca_alive(
    const unsigned char* __restrict__ alpha, float* __restrict__ out)
{
    int t = blockIdx.x * blockDim.x + threadIdx.x;
    if (t >= B_*HW_) return;
    int b = t >> 16;
    int p = t & (HW_-1);
    int i = p >> 8;
    int j = p & (W_-1);
    const unsigned char* ab = alpha + (size_t)b * HW_;

    bool im = i > 0, ip = i < H_-1, jm = j > 0, jp = j < W_-1;
    int acc = ab[p];
    acc += jm ? ab[p-1] : 0;
    acc += jp ? ab[p+1] : 0;
    if (im) {
        acc += ab[p-W_];
        acc += jm ? ab[p-W_-1] : 0;
        acc += jp ? ab[p-W_+1] : 0;
    }
    if (ip) {
        acc += ab[p+W_];
        acc += jm ? ab[p+W_-1] : 0;
        acc += jp ? ab[p+W_+1] : 0;
    }
    if (acc == 0) {
        size_t base = (size_t)b * C_ * HW_ + p;
        #pragma unroll
        for (int c = 0; c < C_; ++c) out[base + (size_t)c * HW_] = 0.f;
    }
}

extern "C" void kernel_launch(void* const* d_in, const int* in_sizes, int n_in,
                              void* d_out, int out_size, void* d_ws, size_t ws_size,
                              hipStream_t stream)
{
    const float* x    = (const float*)d_in[0];
    const int*   mask = (const int*)d_in[1];
    const float* w1   = (const float*)d_in[2];
    const float* b1   = (const float*)d_in[3];
    const float* w2   = (const float*)d_in[4];
    const float* b2   = (const float*)d_in[5];
    float* out = (float*)d_out;

    // ws layout: xs (B*HW floats) | alpha (B*HW bytes) | coef4 (128 float4)
    char* ws = (char*)d_ws;
    float*         xsbuf = (float*)ws;
    unsigned char* alpha = (unsigned char*)(ws + (size_t)B_*HW_*4);
    float4*        coef4 = (float4*)(ws + (size_t)B_*HW_*5);

    nca_prep<<<1, 128, 0, stream>>>(w1, b1, coef4);

    int n4 = B_*HW_/4;
    nca_sum<<<(n4 + 255)/256, 256, 0, stream>>>(x, xsbuf);

    nca_mlp<<<2048, 256, 0, stream>>>(x, mask, xsbuf, coef4, w2, b2, out, alpha);

    int n = B_*HW_;
    nca_alive<<<(n + 255)/256, 256, 0, stream>>>(alpha, out);
}

// Round 4
// 91.168 us; speedup vs baseline: 1.6348x; 1.1636x over previous
//
#include <hip/hip_runtime.h>
#include <hip/hip_bf16.h>

#define B_   32
#define C_   16
#define H_   256
#define W_   256
#define HW_  65536      // H_*W_
#define HID_ 128
#define T_   8          // rows per block
#define NBLK_ (B_*H_/T_)   // 1024 blocks, 32 per image

typedef __attribute__((ext_vector_type(8))) short bf16x8;
typedef __attribute__((ext_vector_type(4))) float f32x4;

__device__ __forceinline__ short f2bf(float f) {
    __hip_bfloat16 h = __float2bfloat16(f);
    return __builtin_bit_cast(short, h);
}

// hardware packed f32->bf16 RNE (no builtin on gfx950)
__device__ __forceinline__ int cvt_pk_bf16(float lo, float hi) {
    int r;
    asm("v_cvt_pk_bf16_f32 %0, %1, %2" : "=v"(r) : "v"(lo), "v"(hi));
    return r;
}

// ---------------- prep: fold w1 into per-o {A,B,C,b1} ------------------------
__global__ __launch_bounds__(128) void nca_prep(
    const float* __restrict__ w1, const float* __restrict__ b1,
    float4* __restrict__ coef4)
{
    int o = threadIdx.x;   // 0..127
    float A = 0.f, Bc = 0.f, Cc = 0.f;
    #pragma unroll
    for (int k = 0;  k < 16; ++k) A  += w1[o*48 + k];
    #pragma unroll
    for (int k = 16; k < 32; ++k) Bc += w1[o*48 + k];
    #pragma unroll
    for (int k = 32; k < 48; ++k) Cc += w1[o*48 + k];
    coef4[o] = make_float4(A, Bc, Cc, b1[o]);
}

// ---------------- fused: channel-sum + sobel + MLP + update + alpha ----------
// Block = 256 threads = one full row width; col = tid. Each block does T_ rows.
// Row sums live in LDS srow[T_+2][W]; x is read ONCE per row for the sum
// (pipelined one row ahead); epilogue re-reads x/mask from L1/L2 (just-summed).
// MFMA layer-2 identical to validated r3 kernel (wave = 64-px strip).
__global__ __launch_bounds__(256, 4) void nca_fused(
    const float* __restrict__ x, const int* __restrict__ mask,
    const float4* __restrict__ coef4, const float* __restrict__ w2,
    const float* __restrict__ b2,
    float* __restrict__ out, unsigned char* __restrict__ alpha)
{
    __shared__ float srow[T_+2][W_];   // 10 KB
    __shared__ short hlds[4*2048];     // 16 KB: per-wave 4KB h-tile / accT

    const int tid  = threadIdx.x;
    const int lane = tid & 63;
    const int widx = tid >> 6;
    const int col  = tid;              // owner column 0..255
    const int q = lane & 15;           // MFMA col lane
    const int g = lane >> 4;           // MFMA k-group

    const int blk = blockIdx.x;
    const int b   = blk >> 5;          // 32 blocks per image
    const int r0  = (blk & 31) * T_;

    const float* xb = x    + (size_t)b * C_ * HW_;
    const int*   mb = mask + (size_t)b * HW_;
    float*       ob = (float*)out + (size_t)b * C_ * HW_;
    unsigned char* ab = alpha + (size_t)b * HW_;

    // A-fragments: w2[ch=q][k = kb*32 + g*8 + j] -> bf16
    bf16x8 afrag[4];
    #pragma unroll
    for (int kb = 0; kb < 4; ++kb) {
        const float* wp = w2 + q*HID_ + kb*32 + g*8;
        bf16x8 a;
        #pragma unroll
        for (int j = 0; j < 8; ++j) a[j] = f2bf(wp[j]);
        afrag[kb] = a;
    }
    f32x4 bias;
    #pragma unroll
    for (int r = 0; r < 4; ++r) bias[r] = b2[g*4 + r];

    const int wswz = (lane ^ (lane >> 2)) & 3;   // h-tile write swizzle
    const int rsw  = (q ^ (q >> 2)) & 3;         // h-tile read swizzle
    short* hw  = hlds + widx*2048;               // 4KB per wave
    char*  hwb = (char*)hw;                      // byte view (accT reuse)

    // ---- prologue: sums for rows r0-1, r0; pipeline loads for r0+1 ----------
    float xnext[C_];
    {
        float s0 = 0.f;
        if (r0 > 0) {
            #pragma unroll
            for (int c = 0; c < C_; ++c)
                s0 += xb[(size_t)c*HW_ + (size_t)(r0-1)*W_ + col];
        }
        float s1 = 0.f;
        #pragma unroll
        for (int c = 0; c < C_; ++c)
            s1 += xb[(size_t)c*HW_ + (size_t)r0*W_ + col];
        #pragma unroll
        for (int c = 0; c < C_; ++c)
            xnext[c] = xb[(size_t)c*HW_ + (size_t)(r0+1)*W_ + col];
        srow[0][col] = s0;
        srow[1][col] = s1;
    }

    for (int r = 0; r < T_; ++r) {
        const int row = r0 + r;

        // finish pipelined sum for row+1 -> slot r+2
        {
            float s = 0.f;
            #pragma unroll
            for (int c = 0; c < C_; ++c) s += xnext[c];
            srow[r+2][col] = s;
        }
        __syncthreads();

        // issue next row's sum loads (row r0+r+2), zero at image bottom halo
        if (r < T_-1) {
            const int nr = r0 + r + 2;
            if (nr < H_) {
                #pragma unroll
                for (int c = 0; c < C_; ++c)
                    xnext[c] = xb[(size_t)c*HW_ + (size_t)nr*W_ + col];
            } else {
                #pragma unroll
                for (int c = 0; c < C_; ++c) xnext[c] = 0.f;
            }
        }

        // ---- sobel on channel-sums from LDS ----
        const bool jm = col > 0, jp = col < W_-1;
        const float* sA = srow[r];
        const float* sB = srow[r+1];
        const float* sC = srow[r+2];
        float n00 = jm ? sA[col-1] : 0.f, n01 = sA[col], n02 = jp ? sA[col+1] : 0.f;
        float n10 = jm ? sB[col-1] : 0.f, n11 = sB[col], n12 = jp ? sB[col+1] : 0.f;
        float n20 = jm ? sC[col-1] : 0.f, n21 = sC[col], n22 = jp ? sC[col+1] : 0.f;
        float px = (n02 - n00) + 2.f*(n12 - n10) + (n22 - n20);
        float py = (n20 - n00) + 2.f*(n21 - n01) + (n22 - n02);
        float sc = n11;

        // ---- layer 1 + MFMA layer 2 (validated structure) ----
        f32x4 acc[4];
        #pragma unroll
        for (int t = 0; t < 4; ++t) acc[t] = bias;

        #pragma unroll
        for (int kb = 0; kb < 4; ++kb) {
            #pragma unroll
            for (int c = 0; c < 4; ++c) {
                float h[8];
                #pragma unroll
                for (int u = 0; u < 8; ++u) {
                    const float4 cf = coef4[kb*32 + c*8 + u];
                    h[u] = fmaxf(fmaf(cf.x, px, fmaf(cf.y, py, fmaf(cf.z, sc, cf.w))), 0.f);
                }
                int4 hd = make_int4(cvt_pk_bf16(h[0], h[1]), cvt_pk_bf16(h[2], h[3]),
                                    cvt_pk_bf16(h[4], h[5]), cvt_pk_bf16(h[6], h[7]));
                *(int4*)(hw + lane*32 + ((c ^ wswz) << 3)) = hd;
            }
            __builtin_amdgcn_wave_barrier();
            #pragma unroll
            for (int t = 0; t < 4; ++t) {
                const int pp = t*16 + q;
                bf16x8 bfrag = *(const bf16x8*)(hw + pp*32 + (((g ^ rsw) & 3) << 3));
                acc[t] = __builtin_amdgcn_mfma_f32_16x16x32_bf16(
                             afrag[kb], bfrag, acc[t], 0, 0, 0);
            }
            __builtin_amdgcn_wave_barrier();
        }

        // ---- acc -> LDS transpose (reuse h-tile; DS pipe is in-order/wave) ---
        // accT[px][chunk u of 4 ch], chunk slot XOR-swizzled by px&3
        #pragma unroll
        for (int t = 0; t < 4; ++t) {
            const int pp = t*16 + q;
            *(f32x4*)(hwb + pp*64 + ((g ^ (pp & 3)) << 4)) = acc[t];
        }
        __builtin_amdgcn_wave_barrier();

        // ---- epilogue: owner lane (px = lane, i.e. this thread's col) --------
        const float m = (float)mb[row*W_ + col];   // L2-hot
        float xn3 = 0.f;
        #pragma unroll
        for (int u = 0; u < 4; ++u) {
            f32x4 a = *(const f32x4*)(hwb + lane*64 + ((u ^ (lane & 3)) << 4));
            #pragma unroll
            for (int e = 0; e < 4; ++e) {
                const int ch = u*4 + e;
                // x re-read: same row summed <1 iter ago -> L1/L2 hit
                float xv = xb[(size_t)ch*HW_ + (size_t)row*W_ + col];
                float xn = fmaf(a[e], m, xv);
                ob[(size_t)ch*HW_ + (size_t)row*W_ + col] = xn;
                if (ch == 3) xn3 = xn;
            }
        }
        ab[row*W_ + col] = (xn3 > 0.1f) ? (unsigned char)1 : (unsigned char)0;
        __builtin_amdgcn_wave_barrier();   // keep next iter's h-writes after reads
    }
}

// ---------------- k3: kill pixels with no alive neighbor ---------------------
__global__ __launch_bounds__(256) void nca_alive(
    const unsigned char* __restrict__ alpha, float* __restrict__ out)
{
    int t = blockIdx.x * blockDim.x + threadIdx.x;
    if (t >= B_*HW_) return;
    int b = t >> 16;
    int p = t & (HW_-1);
    int i = p >> 8;
    int j = p & (W_-1);
    const unsigned char* ab = alpha + (size_t)b * HW_;

    bool im = i > 0, ip = i < H_-1, jm = j > 0, jp = j < W_-1;
    int acc = ab[p];
    acc += jm ? ab[p-1] : 0;
    acc += jp ? ab[p+1] : 0;
    if (im) {
        acc += ab[p-W_];
        acc += jm ? ab[p-W_-1] : 0;
        acc += jp ? ab[p-W_+1] : 0;
    }
    if (ip) {
        acc += ab[p+W_];
        acc += jm ? ab[p+W_-1] : 0;
        acc += jp ? ab[p+W_+1] : 0;
    }
    if (acc == 0) {
        size_t base = (size_t)b * C_ * HW_ + p;
        #pragma unroll
        for (int c = 0; c < C_; ++c) out[base + (size_t)c * HW_] = 0.f;
    }
}

extern "C" void kernel_launch(void* const* d_in, const int* in_sizes, int n_in,
                              void* d_out, int out_size, void* d_ws, size_t ws_size,
                              hipStream_t stream)
{
    const float* x    = (const float*)d_in[0];
    const int*   mask = (const int*)d_in[1];
    const float* w1   = (const float*)d_in[2];
    const float* b1   = (const float*)d_in[3];
    const float* w2   = (const float*)d_in[4];
    const float* b2   = (const float*)d_in[5];
    float* out = (float*)d_out;

    // ws layout: alpha (B*HW bytes) | coef4 (128 float4)
    char* ws = (char*)d_ws;
    unsigned char* alpha = (unsigned char*)ws;
    float4*        coef4 = (float4*)(ws + (size_t)B_*HW_);

    nca_prep<<<1, 128, 0, stream>>>(w1, b1, coef4);

    nca_fused<<<NBLK_, 256, 0, stream>>>(x, mask, coef4, w2, b2, out, alpha);

    int n = B_*HW_;
    nca_alive<<<(n + 255)/256, 256, 0, stream>>>(alpha, out);
}